// Round 11
// baseline (578.571 us; speedup 1.0000x reference)
//
#include <hip/hip_runtime.h>
#include <hip/hip_bf16.h>
#include <cstdint>
#include <cstddef>

#define B_ 64
#define N_ 4096
#define D_ 256
#define S_ 11
#define K_ 128
#define H_ 256
#define ITERS_ 3
#define EPS_ 1e-6f
#define LN_EPS_ 1e-5f
#define SCALE_ 0.08838834764831845f   // 128^-0.5
#define NCH_ 16                        // n-chunks per batch in k45

typedef __bf16 bf16x8 __attribute__((ext_vector_type(8)));
typedef float  f32x4  __attribute__((ext_vector_type(4)));

// native casts -> compiler emits v_cvt_pk_bf16_f32 (RTNE)
__device__ __forceinline__ unsigned short f2bu(float f) {
  __bf16 h = (__bf16)f;
  return __builtin_bit_cast(unsigned short, h);
}
__device__ __forceinline__ unsigned int pk2(float a, float b) {
  return (unsigned int)f2bu(a) | ((unsigned int)f2bu(b) << 16);
}
__device__ __forceinline__ float b2f(unsigned int u16) {
  return __builtin_bit_cast(float, (u16 & 0xffffu) << 16);
}

// ---------------- KPREP: W2pk (lnw-folded) + c1c2 + slots init + packed weights ----------------
__global__ __launch_bounds__(256) void kprep(const float* __restrict__ Wk,
                                             const float* __restrict__ Wv,
                                             const float* __restrict__ lnw,
                                             const float* __restrict__ lnb,
                                             unsigned short* __restrict__ W2pk,
                                             float* __restrict__ c1c2,
                                             const float* __restrict__ si,
                                             const float* __restrict__ mu,
                                             const float* __restrict__ ls,
                                             float* __restrict__ slots,
                                             const float* __restrict__ w_ih,
                                             const float* __restrict__ w_hh,
                                             unsigned int* __restrict__ wihP,
                                             unsigned int* __restrict__ whhP,
                                             const float* __restrict__ w1,
                                             unsigned int* __restrict__ w1P,
                                             const float* __restrict__ w2,
                                             unsigned int* __restrict__ w2P,
                                             const float* __restrict__ Wq,
                                             float* __restrict__ WqT,
                                             unsigned int* __restrict__ WqP) {
  int bid = blockIdx.x, t = threadIdx.x;
  if (bid < 32) {                        // W2pk: 8192 x 16B chunks, lnw folded
    int f = bid * 256 + t;
    int ln_ = f & 63, jj = (f >> 6) & 3, kk2 = (f >> 8) & 1, kt = (f >> 9) & 3, ww = f >> 11;
    int row = ww * 64 + jj * 16 + (ln_ & 15);
    int col = kt * 64 + kk2 * 32 + (ln_ >> 4) * 8;
    const float* src = (row < 128) ? (Wk + row * 256 + col) : (Wv + (row - 128) * 256 + col);
    float4 a = *(const float4*)src;
    float4 b = *(const float4*)(src + 4);
    float4 l0 = *(const float4*)(lnw + col);
    float4 l1 = *(const float4*)(lnw + col + 4);
    a.x *= l0.x; a.y *= l0.y; a.z *= l0.z; a.w *= l0.w;
    b.x *= l1.x; b.y *= l1.y; b.z *= l1.z; b.w *= l1.w;
    uint4 u;
    u.x = pk2(a.x, a.y); u.y = pk2(a.z, a.w); u.z = pk2(b.x, b.y); u.w = pk2(b.z, b.w);
    *(uint4*)(W2pk + (size_t)f * 8) = u;
  } else if (bid < 384) {                // slots init: 90112
    int i = (bid - 32) * 256 + t;
    int k = i & 127;
    slots[i] = mu[k] + __expf(ls[k]) * si[i];
  } else if (bid < 480) {                // wihP: [kkp 0..63][col 0..383] bf16x2
    int i = (bid - 384) * 256 + t;
    int kkp = i & 63, col = i >> 6;
    wihP[kkp * 384 + col] = pk2(w_ih[col * 128 + 2 * kkp], w_ih[col * 128 + 2 * kkp + 1]);
  } else if (bid < 576) {                // whhP
    int i = (bid - 480) * 256 + t;
    int kkp = i & 63, col = i >> 6;
    whhP[kkp * 384 + col] = pk2(w_hh[col * 128 + 2 * kkp], w_hh[col * 128 + 2 * kkp + 1]);
  } else if (bid < 640) {                // w1P: [kkp 0..63][h 0..255]
    int i = (bid - 576) * 256 + t;
    int kkp = i & 63, hc = i >> 6;
    w1P[kkp * 256 + hc] = pk2(w1[hc * 128 + 2 * kkp], w1[hc * 128 + 2 * kkp + 1]);
  } else if (bid < 704) {                // w2P: [hhp 0..127][j 0..127]
    int i = (bid - 640) * 256 + t;
    int j = i & 127, hhp = i >> 7;
    w2P[hhp * 128 + j] = pk2(w2[j * 256 + 2 * hhp], w2[j * 256 + 2 * hhp + 1]);
  } else if (bid < 768) {                // WqT f32 (for k3)
    int i = (bid - 704) * 256 + t;
    int r = i >> 7, c = i & 127;
    WqT[c * 128 + r] = Wq[i];
  } else if (bid < 800) {                // WqP: [mm 0..63][j 0..127]
    int i = (bid - 768) * 256 + t;
    int j = i & 127, mm = i >> 7;
    int kk0 = (mm >> 5) * 64 + (mm & 31) * 2;
    WqP[mm * 128 + j] = pk2(Wq[j * 128 + kk0], Wq[j * 128 + kk0 + 1]);
  } else {                               // c1c2: j = t (0..255)
    int j = t;
    const float* wrow = (j < 128) ? (Wk + j * 256) : (Wv + (j - 128) * 256);
    float c1 = 0.f, c2 = 0.f;
    for (int d = 0; d < 256; d++) {
      float wv = wrow[d];
      c1 += lnb[d] * wv;
      c2 += lnw[d] * wv;
    }
    c1c2[2 * j] = c1;
    c1c2[2 * j + 1] = c2;
  }
}

// ---------------- K12 v7: v4 body + 2-deep (3-buffer) W2pk register prefetch ----------------
__global__ __launch_bounds__(256, 4) void k12_lngemm(const float* __restrict__ x,
                                                     const float* __restrict__ c1c2,
                                                     const unsigned short* __restrict__ W2pk,
                                                     unsigned short* __restrict__ k_frag,
                                                     unsigned short* __restrict__ v_frag) {
  __shared__ char smem[32768];          // x tile bf16 [64 rows][512B], 16B-chunk swizzled
  __shared__ float2 mu_a[64];
  __shared__ float2 ccs[256];
  const int t = threadIdx.x;
  const int lane = t & 63, w = t >> 6;
  const long rowg0 = (long)blockIdx.x * 64;

  ccs[t] = ((const float2*)c1c2)[t];

  bf16x8 wf3[3][4];
  auto loadB = [&](int sstep, bf16x8* dst) {
    const int kt = sstep >> 1, kk = sstep & 1;
#pragma unroll
    for (int jl = 0; jl < 4; jl++)
      dst[jl] = *(const bf16x8*)(W2pk +
          (size_t)((w << 11) | (kt << 9) | (kk << 8) | (jl << 6) | lane) * 8);
  };
  loadB(0, wf3[0]);   // issue early; hides under x streaming
  loadB(1, wf3[1]);

  // ---- phase 1: stream 16 rows per wave, cast, swizzled ds_write. No reductions. ----
  {
    const float* xb = x + (rowg0 + w * 16) * 256 + lane * 4;
#pragma unroll
    for (int rr = 0; rr < 16; rr++) {
      float4 xv = *(const float4*)(xb + rr * 256);
      int r = w * 16 + rr;
      uint2 pk;
      pk.x = pk2(xv.x, xv.y);
      pk.y = pk2(xv.z, xv.w);
      *(uint2*)(smem + r * 512 + (((lane >> 1) ^ (r & 7)) << 4) + ((lane & 1) << 3)) = pk;
    }
  }
  __syncthreads();

  // ---- stats off critical path: 4 threads/row ----
  {
    const int sr = t >> 2, squad = t & 3;
    float s = 0.f, ss = 0.f;
#pragma unroll
    for (int c8 = 0; c8 < 8; c8++) {
      bf16x8 v = *(const bf16x8*)(smem + sr * 512 + ((((squad * 8 + c8) ^ (sr & 7))) << 4));
#pragma unroll
      for (int e = 0; e < 8; e++) {
        float f = (float)v[e];
        s += f; ss += f * f;
      }
    }
    s += __shfl_xor(s, 1);  s += __shfl_xor(s, 2);
    ss += __shfl_xor(ss, 1); ss += __shfl_xor(ss, 2);
    if (squad == 0) {
      float m = s * (1.f / 256.f);
      float var = ss * (1.f / 256.f) - m * m;
      float2 ma; ma.x = m; ma.y = rsqrtf(var + LN_EPS_);
      mu_a[sr] = ma;
    }
  }

  // ---- MFMA: 8 steps, 2-deep W prefetch (3-buffer rotation, fully unrolled) ----
  f32x4 acc[4][4] = {};
#pragma unroll
  for (int sstep = 0; sstep < 8; sstep++) {
    const int kt = sstep >> 1, kk = sstep & 1;
    const bf16x8* cur = wf3[sstep % 3];
    if (sstep < 6) loadB(sstep + 2, wf3[(sstep + 2) % 3]);
    bf16x8 xf[4];
#pragma unroll
    for (int i = 0; i < 4; i++) {
      int row = i * 16 + (lane & 15);
      int slot = (kt * 8 + kk * 4 + (lane >> 4)) ^ (lane & 7);
      xf[i] = *(const bf16x8*)(smem + row * 512 + (slot << 4));
    }
    if (w < 2) {
#pragma unroll
      for (int i = 0; i < 4; i++)
#pragma unroll
        for (int jl = 0; jl < 4; jl++)
          acc[i][jl] = __builtin_amdgcn_mfma_f32_16x16x32_bf16(cur[jl], xf[i], acc[i][jl], 0, 0, 0);
    } else {
#pragma unroll
      for (int i = 0; i < 4; i++)
#pragma unroll
        for (int jl = 0; jl < 4; jl++)
          acc[i][jl] = __builtin_amdgcn_mfma_f32_16x16x32_bf16(xf[i], cur[jl], acc[i][jl], 0, 0, 0);
    }
  }
  __syncthreads();   // mu_a visible to all

  // ---- epilogue: apply LN affine, direct fragment stores ----
  const int ll = lane & 15, lh = lane >> 4;
  if (w < 2) {
    float2 ccr[4][4];
#pragma unroll
    for (int jl = 0; jl < 4; jl++) {
      int jg = w * 4 + jl;
#pragma unroll
      for (int reg = 0; reg < 4; reg++) ccr[jl][reg] = ccs[jg * 16 + lh * 4 + reg];
    }
#pragma unroll
    for (int i = 0; i < 4; i++) {
      float2 ma = mu_a[i * 16 + ll];
#pragma unroll
      for (int jl = 0; jl < 4; jl++) {
        int jg = w * 4 + jl;
        float v0 = ma.y * (acc[i][jl][0] - ma.x * ccr[jl][0].y) + ccr[jl][0].x;
        float v1 = ma.y * (acc[i][jl][1] - ma.x * ccr[jl][1].y) + ccr[jl][1].x;
        float v2 = ma.y * (acc[i][jl][2] - ma.x * ccr[jl][2].y) + ccr[jl][2].x;
        float v3 = ma.y * (acc[i][jl][3] - ma.x * ccr[jl][3].y) + ccr[jl][3].x;
        uint2 pk;
        pk.x = pk2(v0, v1); pk.y = pk2(v2, v3);
        size_t chunk = ((size_t)(rowg0 >> 4) + i) * 4 + (jg >> 1);
        int off = (ll + 16 * ((jg & 1) * 2 + (lh >> 1))) * 8 + (lh & 1) * 4;
        *(uint2*)(k_frag + chunk * 512 + off) = pk;
      }
    }
  } else {
    float2 cj[4];
#pragma unroll
    for (int jl = 0; jl < 4; jl++) cj[jl] = ccs[128 + (w - 2) * 64 + jl * 16 + ll];
#pragma unroll
    for (int i = 0; i < 4; i++) {
      float2 ma0 = mu_a[i * 16 + lh * 4 + 0];
      float2 ma1 = mu_a[i * 16 + lh * 4 + 1];
      float2 ma2 = mu_a[i * 16 + lh * 4 + 2];
      float2 ma3 = mu_a[i * 16 + lh * 4 + 3];
#pragma unroll
      for (int jl = 0; jl < 4; jl++) {
        float v0 = ma0.y * (acc[i][jl][0] - ma0.x * cj[jl].y) + cj[jl].x;
        float v1 = ma1.y * (acc[i][jl][1] - ma1.x * cj[jl].y) + cj[jl].x;
        float v2 = ma2.y * (acc[i][jl][2] - ma2.x * cj[jl].y) + cj[jl].x;
        float v3 = ma3.y * (acc[i][jl][3] - ma3.x * cj[jl].y) + cj[jl].x;
        uint2 pk;
        pk.x = pk2(v0, v1); pk.y = pk2(v2, v3);
        size_t chunk = ((size_t)(rowg0 >> 5) + (i >> 1)) * 8 + (w - 2) * 4 + jl;
        int off = (ll + 16 * ((i & 1) * 2 + (lh >> 1))) * 8 + (lh & 1) * 4;
        *(uint2*)(v_frag + chunk * 512 + off) = pk;
      }
    }
  }
}

// ---------------- reduce helper: sum over 128 threads ----------------
__device__ __forceinline__ float redsum128(float v, float* red2) {
#pragma unroll
  for (int o = 1; o < 64; o <<= 1) v += __shfl_xor(v, o);
  __syncthreads();
  if ((threadIdx.x & 63) == 0) red2[threadIdx.x >> 6] = v;
  __syncthreads();
  return red2[0] + red2[1];
}

// ---------------- K3: initial q (iter 0 only) ----------------
__global__ __launch_bounds__(128) void k3_q(const float* __restrict__ slots,
                                            const float* __restrict__ lw,
                                            const float* __restrict__ lb,
                                            const float* __restrict__ WqT,
                                            float* __restrict__ q) {
  int bs = blockIdx.x;
  int j = threadIdx.x;
  __shared__ float sn[128];
  __shared__ float red2[2];
  float x = slots[(size_t)bs * 128 + j];
  float sum = redsum128(x, red2);
  float sq  = redsum128(x * x, red2);
  float mean = sum * (1.f / 128.f);
  float var  = sq * (1.f / 128.f) - mean * mean;
  float v = (x - mean) * rsqrtf(var + LN_EPS_) * lw[j] + lb[j];
  sn[j] = v;
  __syncthreads();
  float acc = 0.f;
#pragma unroll 8
  for (int kk = 0; kk < 128; kk++) acc += sn[kk] * WqT[kk * 128 + j];
  q[(size_t)bs * 128 + j] = acc;
}

// ---------------- K45: logits(MFMA) + softmax + updates(MFMA), fragment inputs ----------------
__global__ __launch_bounds__(256) void k45_attn(const unsigned short* __restrict__ k_frag,
                                                const unsigned short* __restrict__ v_frag,
                                                const float* __restrict__ qbuf,
                                                float* __restrict__ num_part,
                                                float* __restrict__ den_part) {
  __shared__ unsigned short att[16 * 264];   // stride 264 bf16 (528B)
  __shared__ float redd[4][16];
  const int t = threadIdx.x;
  const int lane = t & 63, w = t >> 6;
  const int b = blockIdx.x >> 4, chunk = blockIdx.x & (NCH_ - 1);

  int sqi = lane & 15; if (sqi > 10) sqi = 10;
  const float* qp = qbuf + ((size_t)b * S_ + sqi) * 128 + (lane >> 4) * 8;
  bf16x8 qf[4];
#pragma unroll
  for (int ks = 0; ks < 4; ks++) {
    float4 q0 = *(const float4*)(qp + ks * 32);
    float4 q1 = *(const float4*)(qp + ks * 32 + 4);
    uint4 uu;
    uu.x = pk2(q0.x, q0.y); uu.y = pk2(q0.z, q0.w);
    uu.z = pk2(q1.x, q1.y); uu.w = pk2(q1.z, q1.w);
    qf[ks] = __builtin_bit_cast(bf16x8, uu);
  }
  const bool dead = (lane & 15) >= 11;
  float dden = 0.f;

#pragma unroll
  for (int u = 0; u < 4; u++) {
    size_t g = (size_t)b * 256 + chunk * 16 + w * 4 + u;
    f32x4 lg = {0.f, 0.f, 0.f, 0.f};
#pragma unroll
    for (int ks = 0; ks < 4; ks++) {
      bf16x8 af = *(const bf16x8*)(k_frag + (g * 4 + ks) * 512 + lane * 8);
      lg = __builtin_amdgcn_mfma_f32_16x16x32_bf16(af, qf[ks], lg, 0, 0, 0);
    }
    float l0 = dead ? -1e30f : lg[0] * SCALE_;
    float l1 = dead ? -1e30f : lg[1] * SCALE_;
    float l2 = dead ? -1e30f : lg[2] * SCALE_;
    float l3 = dead ? -1e30f : lg[3] * SCALE_;
    float m0 = l0, m1 = l1, m2 = l2, m3 = l3;
#pragma unroll
    for (int o = 1; o < 16; o <<= 1) {
      m0 = fmaxf(m0, __shfl_xor(m0, o)); m1 = fmaxf(m1, __shfl_xor(m1, o));
      m2 = fmaxf(m2, __shfl_xor(m2, o)); m3 = fmaxf(m3, __shfl_xor(m3, o));
    }
    float e0 = __expf(l0 - m0), e1 = __expf(l1 - m1);
    float e2 = __expf(l2 - m2), e3 = __expf(l3 - m3);
    float t0 = e0, t1 = e1, t2 = e2, t3 = e3;
#pragma unroll
    for (int o = 1; o < 16; o <<= 1) {
      t0 += __shfl_xor(t0, o); t1 += __shfl_xor(t1, o);
      t2 += __shfl_xor(t2, o); t3 += __shfl_xor(t3, o);
    }
    float a0 = e0 / t0 + EPS_, a1 = e1 / t1 + EPS_;
    float a2 = e2 / t2 + EPS_, a3 = e3 / t3 + EPS_;
    dden += a0 + a1 + a2 + a3;
    uint2 pk;
    pk.x = pk2(a0, a1); pk.y = pk2(a2, a3);
    int s = lane & 15;
    int nn = w * 64 + u * 16 + (lane >> 4) * 4;
    *(uint2*)((char*)att + s * 528 + nn * 2) = pk;
  }
  dden += __shfl_xor(dden, 16);
  dden += __shfl_xor(dden, 32);
  if (lane < 16) redd[w][lane] = dden;
  __syncthreads();
  if (t < S_)
    den_part[((size_t)b * NCH_ + chunk) * S_ + t] =
        redd[0][t] + redd[1][t] + redd[2][t] + redd[3][t];

  f32x4 acc[2] = {};
#pragma unroll
  for (int ks = 0; ks < 8; ks++) {
    bf16x8 pa = *(const bf16x8*)((const char*)att + (lane & 15) * 528 +
                                 (ks * 32 + (lane >> 4) * 8) * 2);
    size_t nb = (size_t)b * 128 + chunk * 8 + ks;
#pragma unroll
    for (int j = 0; j < 2; j++) {
      bf16x8 vb = *(const bf16x8*)(v_frag + (nb * 8 + (w * 2 + j)) * 512 + lane * 8);
      acc[j] = __builtin_amdgcn_mfma_f32_16x16x32_bf16(pa, vb, acc[j], 0, 0, 0);
    }
  }
#pragma unroll
  for (int j = 0; j < 2; j++)
#pragma unroll
    for (int r = 0; r < 4; r++) {
      int s = (lane >> 4) * 4 + r;
      if (s < S_) {
        int k = w * 32 + j * 16 + (lane & 15);
        num_part[(((size_t)b * NCH_ + chunk) * S_ + s) * 128 + k] = acc[j][r];
      }
    }
}

// ---------------- K63: finalize, GRU, MLP -> slots; packed bf16 weights ----------------
__global__ __launch_bounds__(256) void k63_final(const float* __restrict__ num_part,
                                                 const float* __restrict__ den_part,
                                                 float* __restrict__ slots,
                                                 const unsigned int* __restrict__ wihP,
                                                 const unsigned int* __restrict__ whhP,
                                                 const float* __restrict__ b_ih,
                                                 const float* __restrict__ b_hh,
                                                 const float* __restrict__ lmw,
                                                 const float* __restrict__ lmb,
                                                 const unsigned int* __restrict__ w1P,
                                                 const float* __restrict__ bb1,
                                                 const unsigned int* __restrict__ w2P,
                                                 const float* __restrict__ bb2,
                                                 const float* __restrict__ lsw,
                                                 const float* __restrict__ lsb,
                                                 const unsigned int* __restrict__ WqP,
                                                 float* __restrict__ qbuf,
                                                 float* __restrict__ outp,
                                                 int cq, int wout) {
  int bs = blockIdx.x;
  int b = bs / S_, s = bs % S_;
  int t = threadIdx.x;
  int j = t & 127, half = t >> 7;
  __shared__ float u[128], h[128], gp[3][128], m[128], hid[256], sjs[128], op[128];
  __shared__ float ns[128], snq[128];
  __shared__ float red2a[2], red2b[2];

  if (half == 0) {
    float den = 0.f;
#pragma unroll
    for (int c = 0; c < NCH_; c++) den += den_part[((size_t)b * NCH_ + c) * S_ + s];
    float uj = 0.f;
#pragma unroll
    for (int c = 0; c < NCH_; c++) uj += num_part[(((size_t)b * NCH_ + c) * S_ + s) * 128 + j];
    u[j] = uj / den;
  } else {
    h[j] = slots[((size_t)b * S_ + s) * 128 + j];
  }
  __syncthreads();

  {
    const unsigned int* wP = half ? whhP : wihP;
    const float* sv = half ? h : u;
    float g0 = 0.f, g1 = 0.f, g2 = 0.f;
#pragma unroll 8
    for (int kkp = 0; kkp < 64; kkp++) {
      float s0 = sv[2 * kkp], s1 = sv[2 * kkp + 1];
      unsigned int a0 = wP[kkp * 384 + j];
      unsigned int a1 = wP[kkp * 384 + 128 + j];
      unsigned int a2 = wP[kkp * 384 + 256 + j];
      g0 += b2f(a0) * s0 + b2f(a0 >> 16) * s1;
      g1 += b2f(a1) * s0 + b2f(a1 >> 16) * s1;
      g2 += b2f(a2) * s0 + b2f(a2 >> 16) * s1;
    }
    if (half) { gp[0][j] = g0; gp[1][j] = g1; gp[2][j] = g2; }
    __syncthreads();
    float sj = 0.f;
    if (half == 0) {
      float gr = g0 + b_ih[j]       + gp[0][j] + b_hh[j];
      float gz = g1 + b_ih[128 + j] + gp[1][j] + b_hh[128 + j];
      float r = 1.f / (1.f + __expf(-gr));
      float z = 1.f / (1.f + __expf(-gz));
      float nn = tanhf(g2 + b_ih[256 + j] + r * (gp[2][j] + b_hh[256 + j]));
      sj = (1.f - z) * nn + z * h[j];
      sjs[j] = sj;
    }
    float sv2 = sj, sq2 = sj * sj;
#pragma unroll
    for (int o = 1; o < 64; o <<= 1) { sv2 += __shfl_xor(sv2, o); sq2 += __shfl_xor(sq2, o); }
    if (half == 0 && (t & 63) == 0) { red2a[t >> 6] = sv2; red2b[t >> 6] = sq2; }
    __syncthreads();
    float mean = (red2a[0] + red2a[1]) * (1.f / 128.f);
    float var  = (red2b[0] + red2b[1]) * (1.f / 128.f) - mean * mean;
    float rstd = rsqrtf(var + LN_EPS_);
    if (half == 0) m[j] = (sj - mean) * rstd * lmw[j] + lmb[j];
  }
  __syncthreads();

  {
    float a = bb1[t];
#pragma unroll 8
    for (int kkp = 0; kkp < 64; kkp++) {
      unsigned int wv = w1P[kkp * 256 + t];
      a += b2f(wv) * m[2 * kkp] + b2f(wv >> 16) * m[2 * kkp + 1];
    }
    hid[t] = fmaxf(a, 0.f);
  }
  __syncthreads();

  {
    const float* hp = hid + half * 128;
    float o2 = 0.f;
#pragma unroll 8
    for (int hhp = 0; hhp < 64; hhp++) {
      unsigned int wv = w2P[(half * 64 + hhp) * 128 + j];
      o2 += b2f(wv) * hp[2 * hhp] + b2f(wv >> 16) * hp[2 * hhp + 1];
    }
    if (half) op[j] = o2;
    __syncthreads();
    if (half == 0) {
      float ov = sjs[j] + bb2[j] + o2 + op[j];
      slots[((size_t)b * S_ + s) * 128 + j] = ov;
      if (wout) outp[((size_t)b * S_ + s) * 128 + j] = ov;
      ns[j] = ov;
    }
  }
  __syncthreads();

  if (cq) {   // fused q for next iteration: q = LN_slot(new_slots) * Wq^T
    float vv = (half == 0) ? ns[j] : 0.f;
    float s1 = vv, s2 = vv * vv;
#pragma unroll
    for (int o = 1; o < 64; o <<= 1) { s1 += __shfl_xor(s1, o); s2 += __shfl_xor(s2, o); }
    if (half == 0 && (t & 63) == 0) { red2a[t >> 6] = s1; red2b[t >> 6] = s2; }
    __syncthreads();
    float mean = (red2a[0] + red2a[1]) * (1.f / 128.f);
    float var  = (red2b[0] + red2b[1]) * (1.f / 128.f) - mean * mean;
    float rstd = rsqrtf(var + LN_EPS_);
    if (half == 0) snq[j] = (ns[j] - mean) * rstd * lsw[j] + lsb[j];
    __syncthreads();
    const float* sp = snq + half * 64;
    float qv = 0.f;
#pragma unroll 8
    for (int m2 = 0; m2 < 32; m2++) {
      unsigned int wv = WqP[(half * 32 + m2) * 128 + j];
      qv += b2f(wv) * sp[2 * m2] + b2f(wv >> 16) * sp[2 * m2 + 1];
    }
    if (half) op[j] = qv;
    __syncthreads();
    if (half == 0) qbuf[(size_t)bs * 128 + j] = qv + op[j];
  }
}

extern "C" void kernel_launch(void* const* d_in, const int* in_sizes, int n_in,
                              void* d_out, int out_size, void* d_ws, size_t ws_size,
                              hipStream_t stream) {
  (void)in_sizes; (void)n_in; (void)out_size; (void)ws_size;
  const float* inputs     = (const float*)d_in[0];
  const float* slots_init = (const float*)d_in[1];
  const float* slots_mu   = (const float*)d_in[2];
  const float* slots_ls   = (const float*)d_in[3];
  const float* ln_in_w    = (const float*)d_in[4];
  const float* ln_in_b    = (const float*)d_in[5];
  const float* ln_slot_w  = (const float*)d_in[6];
  const float* ln_slot_b  = (const float*)d_in[7];
  const float* ln_mlp_w   = (const float*)d_in[8];
  const float* ln_mlp_b   = (const float*)d_in[9];
  const float* Wq         = (const float*)d_in[10];
  const float* Wk         = (const float*)d_in[11];
  const float* Wv         = (const float*)d_in[12];
  const float* w_ih       = (const float*)d_in[13];
  const float* w_hh       = (const float*)d_in[14];
  const float* b_ih       = (const float*)d_in[15];
  const float* b_hh       = (const float*)d_in[16];
  const float* mlp_w1     = (const float*)d_in[17];
  const float* mlp_b1     = (const float*)d_in[18];
  const float* mlp_w2     = (const float*)d_in[19];
  const float* mlp_b2     = (const float*)d_in[20];

  uintptr_t p = (uintptr_t)d_ws;
  auto carve = [&](size_t bytes) -> void* {
    void* r = (void*)p;
    p += (bytes + 255) & ~(size_t)255;
    return r;
  };
  unsigned short* k_frag = (unsigned short*)carve((size_t)B_ * N_ * K_ * 2);
  unsigned short* v_frag = (unsigned short*)carve((size_t)B_ * K_ * N_ * 2);
  unsigned short* W2pk   = (unsigned short*)carve((size_t)256 * 256 * 2);
  float* c1c2  = (float*)carve((size_t)256 * 2 * 4);
  unsigned int* wihP = (unsigned int*)carve((size_t)64 * 384 * 4);
  unsigned int* whhP = (unsigned int*)carve((size_t)64 * 384 * 4);
  unsigned int* w1P  = (unsigned int*)carve((size_t)64 * 256 * 4);
  unsigned int* w2P  = (unsigned int*)carve((size_t)128 * 128 * 4);
  unsigned int* WqP  = (unsigned int*)carve((size_t)64 * 128 * 4);
  float* WqT   = (float*)carve((size_t)128 * 128 * 4);
  float* qbuf     = (float*)carve((size_t)B_ * S_ * K_ * 4);
  float* slots    = (float*)carve((size_t)B_ * S_ * K_ * 4);
  float* den_part = (float*)carve((size_t)B_ * NCH_ * S_ * 4);
  float* num_part = (float*)carve((size_t)B_ * NCH_ * S_ * K_ * 4);

  kprep<<<801, 256, 0, stream>>>(Wk, Wv, ln_in_w, ln_in_b, W2pk, c1c2,
                                 slots_init, slots_mu, slots_ls, slots,
                                 w_ih, w_hh, wihP, whhP, mlp_w1, w1P, mlp_w2, w2P,
                                 Wq, WqT, WqP);
  k12_lngemm<<<(B_ * N_) / 64, 256, 0, stream>>>(inputs, c1c2, W2pk, k_frag, v_frag);
  k3_q<<<B_ * S_, 128, 0, stream>>>(slots, ln_slot_w, ln_slot_b, WqT, qbuf);

  for (int it = 0; it < ITERS_; ++it) {
    k45_attn<<<B_ * NCH_, 256, 0, stream>>>(k_frag, v_frag, qbuf, num_part, den_part);
    k63_final<<<B_ * S_, 256, 0, stream>>>(num_part, den_part, slots,
                                           wihP, whhP, b_ih, b_hh,
                                           ln_mlp_w, ln_mlp_b,
                                           w1P, mlp_b1, w2P, mlp_b2,
                                           ln_slot_w, ln_slot_b, WqP, qbuf,
                                           (float*)d_out,
                                           (it < ITERS_ - 1) ? 1 : 0,
                                           (it == ITERS_ - 1) ? 1 : 0);
  }
}

// Round 12
// 229.882 us; speedup vs baseline: 2.5168x; 2.5168x over previous
//
#include <hip/hip_runtime.h>
#include <hip/hip_bf16.h>
#include <cstdint>
#include <cstddef>

#define B_ 64
#define N_ 4096
#define D_ 256
#define S_ 11
#define K_ 128
#define H_ 256
#define ITERS_ 3
#define EPS_ 1e-6f
#define LN_EPS_ 1e-5f
#define SCALE_ 0.08838834764831845f   // 128^-0.5
#define NCH_ 16                        // n-chunks per batch in k45

typedef __bf16 bf16x8 __attribute__((ext_vector_type(8)));
typedef float  f32x4  __attribute__((ext_vector_type(4)));

// native casts -> compiler emits v_cvt_pk_bf16_f32 (RTNE)
__device__ __forceinline__ unsigned short f2bu(float f) {
  __bf16 h = (__bf16)f;
  return __builtin_bit_cast(unsigned short, h);
}
__device__ __forceinline__ unsigned int pk2(float a, float b) {
  return (unsigned int)f2bu(a) | ((unsigned int)f2bu(b) << 16);
}
__device__ __forceinline__ float b2f(unsigned int u16) {
  return __builtin_bit_cast(float, (u16 & 0xffffu) << 16);
}

// ---------------- KPREP: W2pk (lnw-folded) + c1c2 + slots init + packed weights ----------------
__global__ __launch_bounds__(256) void kprep(const float* __restrict__ Wk,
                                             const float* __restrict__ Wv,
                                             const float* __restrict__ lnw,
                                             const float* __restrict__ lnb,
                                             unsigned short* __restrict__ W2pk,
                                             float* __restrict__ c1c2,
                                             const float* __restrict__ si,
                                             const float* __restrict__ mu,
                                             const float* __restrict__ ls,
                                             float* __restrict__ slots,
                                             const float* __restrict__ w_ih,
                                             const float* __restrict__ w_hh,
                                             unsigned int* __restrict__ wihP,
                                             unsigned int* __restrict__ whhP,
                                             const float* __restrict__ w1,
                                             unsigned int* __restrict__ w1P,
                                             const float* __restrict__ w2,
                                             unsigned int* __restrict__ w2P,
                                             const float* __restrict__ Wq,
                                             float* __restrict__ WqT,
                                             unsigned int* __restrict__ WqP) {
  int bid = blockIdx.x, t = threadIdx.x;
  if (bid < 32) {                        // W2pk: 8192 x 16B chunks, lnw folded
    int f = bid * 256 + t;
    int ln_ = f & 63, jj = (f >> 6) & 3, kk2 = (f >> 8) & 1, kt = (f >> 9) & 3, ww = f >> 11;
    int row = ww * 64 + jj * 16 + (ln_ & 15);
    int col = kt * 64 + kk2 * 32 + (ln_ >> 4) * 8;
    const float* src = (row < 128) ? (Wk + row * 256 + col) : (Wv + (row - 128) * 256 + col);
    float4 a = *(const float4*)src;
    float4 b = *(const float4*)(src + 4);
    float4 l0 = *(const float4*)(lnw + col);
    float4 l1 = *(const float4*)(lnw + col + 4);
    a.x *= l0.x; a.y *= l0.y; a.z *= l0.z; a.w *= l0.w;
    b.x *= l1.x; b.y *= l1.y; b.z *= l1.z; b.w *= l1.w;
    uint4 u;
    u.x = pk2(a.x, a.y); u.y = pk2(a.z, a.w); u.z = pk2(b.x, b.y); u.w = pk2(b.z, b.w);
    *(uint4*)(W2pk + (size_t)f * 8) = u;
  } else if (bid < 384) {                // slots init: 90112
    int i = (bid - 32) * 256 + t;
    int k = i & 127;
    slots[i] = mu[k] + __expf(ls[k]) * si[i];
  } else if (bid < 480) {                // wihP: [kkp 0..63][col 0..383] bf16x2
    int i = (bid - 384) * 256 + t;
    int kkp = i & 63, col = i >> 6;
    wihP[kkp * 384 + col] = pk2(w_ih[col * 128 + 2 * kkp], w_ih[col * 128 + 2 * kkp + 1]);
  } else if (bid < 576) {                // whhP
    int i = (bid - 480) * 256 + t;
    int kkp = i & 63, col = i >> 6;
    whhP[kkp * 384 + col] = pk2(w_hh[col * 128 + 2 * kkp], w_hh[col * 128 + 2 * kkp + 1]);
  } else if (bid < 640) {                // w1P: [kkp 0..63][h 0..255]
    int i = (bid - 576) * 256 + t;
    int kkp = i & 63, hc = i >> 6;
    w1P[kkp * 256 + hc] = pk2(w1[hc * 128 + 2 * kkp], w1[hc * 128 + 2 * kkp + 1]);
  } else if (bid < 704) {                // w2P: [hhp 0..127][j 0..127]
    int i = (bid - 640) * 256 + t;
    int j = i & 127, hhp = i >> 7;
    w2P[hhp * 128 + j] = pk2(w2[j * 256 + 2 * hhp], w2[j * 256 + 2 * hhp + 1]);
  } else if (bid < 768) {                // WqT f32 (for k3)
    int i = (bid - 704) * 256 + t;
    int r = i >> 7, c = i & 127;
    WqT[c * 128 + r] = Wq[i];
  } else if (bid < 800) {                // WqP: [mm 0..63][j 0..127]
    int i = (bid - 768) * 256 + t;
    int j = i & 127, mm = i >> 7;
    int kk0 = (mm >> 5) * 64 + (mm & 31) * 2;
    WqP[mm * 128 + j] = pk2(Wq[j * 128 + kk0], Wq[j * 128 + kk0 + 1]);
  } else {                               // c1c2: j = t (0..255)
    int j = t;
    const float* wrow = (j < 128) ? (Wk + j * 256) : (Wv + (j - 128) * 256);
    float c1 = 0.f, c2 = 0.f;
    for (int d = 0; d < 256; d++) {
      float wv = wrow[d];
      c1 += lnb[d] * wv;
      c2 += lnw[d] * wv;
    }
    c1c2[2 * j] = c1;
    c1c2[2 * j + 1] = c2;
  }
}

// ---------------- K12 v7b: v4 body + 2-deep (3-buffer) W2pk prefetch, NO reg cap ----------------
__global__ __launch_bounds__(256) void k12_lngemm(const float* __restrict__ x,
                                                  const float* __restrict__ c1c2,
                                                  const unsigned short* __restrict__ W2pk,
                                                  unsigned short* __restrict__ k_frag,
                                                  unsigned short* __restrict__ v_frag) {
  __shared__ char smem[32768];          // x tile bf16 [64 rows][512B], 16B-chunk swizzled
  __shared__ float2 mu_a[64];
  __shared__ float2 ccs[256];
  const int t = threadIdx.x;
  const int lane = t & 63, w = t >> 6;
  const long rowg0 = (long)blockIdx.x * 64;

  ccs[t] = ((const float2*)c1c2)[t];

  bf16x8 wf3[3][4];
  auto loadB = [&](int sstep, bf16x8* dst) {
    const int kt = sstep >> 1, kk = sstep & 1;
#pragma unroll
    for (int jl = 0; jl < 4; jl++)
      dst[jl] = *(const bf16x8*)(W2pk +
          (size_t)((w << 11) | (kt << 9) | (kk << 8) | (jl << 6) | lane) * 8);
  };
  loadB(0, wf3[0]);   // issue early; hides under x streaming
  loadB(1, wf3[1]);

  // ---- phase 1: stream 16 rows per wave, cast, swizzled ds_write. No reductions. ----
  {
    const float* xb = x + (rowg0 + w * 16) * 256 + lane * 4;
#pragma unroll
    for (int rr = 0; rr < 16; rr++) {
      float4 xv = *(const float4*)(xb + rr * 256);
      int r = w * 16 + rr;
      uint2 pk;
      pk.x = pk2(xv.x, xv.y);
      pk.y = pk2(xv.z, xv.w);
      *(uint2*)(smem + r * 512 + (((lane >> 1) ^ (r & 7)) << 4) + ((lane & 1) << 3)) = pk;
    }
  }
  __syncthreads();

  // ---- stats off critical path: 4 threads/row ----
  {
    const int sr = t >> 2, squad = t & 3;
    float s = 0.f, ss = 0.f;
#pragma unroll
    for (int c8 = 0; c8 < 8; c8++) {
      bf16x8 v = *(const bf16x8*)(smem + sr * 512 + ((((squad * 8 + c8) ^ (sr & 7))) << 4));
#pragma unroll
      for (int e = 0; e < 8; e++) {
        float f = (float)v[e];
        s += f; ss += f * f;
      }
    }
    s += __shfl_xor(s, 1);  s += __shfl_xor(s, 2);
    ss += __shfl_xor(ss, 1); ss += __shfl_xor(ss, 2);
    if (squad == 0) {
      float m = s * (1.f / 256.f);
      float var = ss * (1.f / 256.f) - m * m;
      float2 ma; ma.x = m; ma.y = rsqrtf(var + LN_EPS_);
      mu_a[sr] = ma;
    }
  }

  // ---- MFMA: 8 steps, 2-deep W prefetch (3-buffer rotation, fully unrolled) ----
  f32x4 acc[4][4] = {};
#pragma unroll
  for (int sstep = 0; sstep < 8; sstep++) {
    const int kt = sstep >> 1, kk = sstep & 1;
    const bf16x8* cur = wf3[sstep % 3];
    if (sstep < 6) loadB(sstep + 2, wf3[(sstep + 2) % 3]);
    bf16x8 xf[4];
#pragma unroll
    for (int i = 0; i < 4; i++) {
      int row = i * 16 + (lane & 15);
      int slot = (kt * 8 + kk * 4 + (lane >> 4)) ^ (lane & 7);
      xf[i] = *(const bf16x8*)(smem + row * 512 + (slot << 4));
    }
    if (w < 2) {
#pragma unroll
      for (int i = 0; i < 4; i++)
#pragma unroll
        for (int jl = 0; jl < 4; jl++)
          acc[i][jl] = __builtin_amdgcn_mfma_f32_16x16x32_bf16(cur[jl], xf[i], acc[i][jl], 0, 0, 0);
    } else {
#pragma unroll
      for (int i = 0; i < 4; i++)
#pragma unroll
        for (int jl = 0; jl < 4; jl++)
          acc[i][jl] = __builtin_amdgcn_mfma_f32_16x16x32_bf16(xf[i], cur[jl], acc[i][jl], 0, 0, 0);
    }
  }
  __syncthreads();   // mu_a visible to all

  // ---- epilogue: apply LN affine, direct fragment stores ----
  const int ll = lane & 15, lh = lane >> 4;
  if (w < 2) {
    float2 ccr[4][4];
#pragma unroll
    for (int jl = 0; jl < 4; jl++) {
      int jg = w * 4 + jl;
#pragma unroll
      for (int reg = 0; reg < 4; reg++) ccr[jl][reg] = ccs[jg * 16 + lh * 4 + reg];
    }
#pragma unroll
    for (int i = 0; i < 4; i++) {
      float2 ma = mu_a[i * 16 + ll];
#pragma unroll
      for (int jl = 0; jl < 4; jl++) {
        int jg = w * 4 + jl;
        float v0 = ma.y * (acc[i][jl][0] - ma.x * ccr[jl][0].y) + ccr[jl][0].x;
        float v1 = ma.y * (acc[i][jl][1] - ma.x * ccr[jl][1].y) + ccr[jl][1].x;
        float v2 = ma.y * (acc[i][jl][2] - ma.x * ccr[jl][2].y) + ccr[jl][2].x;
        float v3 = ma.y * (acc[i][jl][3] - ma.x * ccr[jl][3].y) + ccr[jl][3].x;
        uint2 pk;
        pk.x = pk2(v0, v1); pk.y = pk2(v2, v3);
        size_t chunk = ((size_t)(rowg0 >> 4) + i) * 4 + (jg >> 1);
        int off = (ll + 16 * ((jg & 1) * 2 + (lh >> 1))) * 8 + (lh & 1) * 4;
        *(uint2*)(k_frag + chunk * 512 + off) = pk;
      }
    }
  } else {
    float2 cj[4];
#pragma unroll
    for (int jl = 0; jl < 4; jl++) cj[jl] = ccs[128 + (w - 2) * 64 + jl * 16 + ll];
#pragma unroll
    for (int i = 0; i < 4; i++) {
      float2 ma0 = mu_a[i * 16 + lh * 4 + 0];
      float2 ma1 = mu_a[i * 16 + lh * 4 + 1];
      float2 ma2 = mu_a[i * 16 + lh * 4 + 2];
      float2 ma3 = mu_a[i * 16 + lh * 4 + 3];
#pragma unroll
      for (int jl = 0; jl < 4; jl++) {
        float v0 = ma0.y * (acc[i][jl][0] - ma0.x * cj[jl].y) + cj[jl].x;
        float v1 = ma1.y * (acc[i][jl][1] - ma1.x * cj[jl].y) + cj[jl].x;
        float v2 = ma2.y * (acc[i][jl][2] - ma2.x * cj[jl].y) + cj[jl].x;
        float v3 = ma3.y * (acc[i][jl][3] - ma3.x * cj[jl].y) + cj[jl].x;
        uint2 pk;
        pk.x = pk2(v0, v1); pk.y = pk2(v2, v3);
        size_t chunk = ((size_t)(rowg0 >> 5) + (i >> 1)) * 8 + (w - 2) * 4 + jl;
        int off = (ll + 16 * ((i & 1) * 2 + (lh >> 1))) * 8 + (lh & 1) * 4;
        *(uint2*)(v_frag + chunk * 512 + off) = pk;
      }
    }
  }
}

// ---------------- reduce helper: sum over 128 threads ----------------
__device__ __forceinline__ float redsum128(float v, float* red2) {
#pragma unroll
  for (int o = 1; o < 64; o <<= 1) v += __shfl_xor(v, o);
  __syncthreads();
  if ((threadIdx.x & 63) == 0) red2[threadIdx.x >> 6] = v;
  __syncthreads();
  return red2[0] + red2[1];
}

// ---------------- K3: initial q (iter 0 only) ----------------
__global__ __launch_bounds__(128) void k3_q(const float* __restrict__ slots,
                                            const float* __restrict__ lw,
                                            const float* __restrict__ lb,
                                            const float* __restrict__ WqT,
                                            float* __restrict__ q) {
  int bs = blockIdx.x;
  int j = threadIdx.x;
  __shared__ float sn[128];
  __shared__ float red2[2];
  float x = slots[(size_t)bs * 128 + j];
  float sum = redsum128(x, red2);
  float sq  = redsum128(x * x, red2);
  float mean = sum * (1.f / 128.f);
  float var  = sq * (1.f / 128.f) - mean * mean;
  float v = (x - mean) * rsqrtf(var + LN_EPS_) * lw[j] + lb[j];
  sn[j] = v;
  __syncthreads();
  float acc = 0.f;
#pragma unroll 8
  for (int kk = 0; kk < 128; kk++) acc += sn[kk] * WqT[kk * 128 + j];
  q[(size_t)bs * 128 + j] = acc;
}

// ---------------- K45: logits(MFMA) + softmax + updates(MFMA), fragment inputs ----------------
__global__ __launch_bounds__(256) void k45_attn(const unsigned short* __restrict__ k_frag,
                                                const unsigned short* __restrict__ v_frag,
                                                const float* __restrict__ qbuf,
                                                float* __restrict__ num_part,
                                                float* __restrict__ den_part) {
  __shared__ unsigned short att[16 * 264];   // stride 264 bf16 (528B)
  __shared__ float redd[4][16];
  const int t = threadIdx.x;
  const int lane = t & 63, w = t >> 6;
  const int b = blockIdx.x >> 4, chunk = blockIdx.x & (NCH_ - 1);

  int sqi = lane & 15; if (sqi > 10) sqi = 10;
  const float* qp = qbuf + ((size_t)b * S_ + sqi) * 128 + (lane >> 4) * 8;
  bf16x8 qf[4];
#pragma unroll
  for (int ks = 0; ks < 4; ks++) {
    float4 q0 = *(const float4*)(qp + ks * 32);
    float4 q1 = *(const float4*)(qp + ks * 32 + 4);
    uint4 uu;
    uu.x = pk2(q0.x, q0.y); uu.y = pk2(q0.z, q0.w);
    uu.z = pk2(q1.x, q1.y); uu.w = pk2(q1.z, q1.w);
    qf[ks] = __builtin_bit_cast(bf16x8, uu);
  }
  const bool dead = (lane & 15) >= 11;
  float dden = 0.f;

#pragma unroll
  for (int u = 0; u < 4; u++) {
    size_t g = (size_t)b * 256 + chunk * 16 + w * 4 + u;
    f32x4 lg = {0.f, 0.f, 0.f, 0.f};
#pragma unroll
    for (int ks = 0; ks < 4; ks++) {
      bf16x8 af = *(const bf16x8*)(k_frag + (g * 4 + ks) * 512 + lane * 8);
      lg = __builtin_amdgcn_mfma_f32_16x16x32_bf16(af, qf[ks], lg, 0, 0, 0);
    }
    float l0 = dead ? -1e30f : lg[0] * SCALE_;
    float l1 = dead ? -1e30f : lg[1] * SCALE_;
    float l2 = dead ? -1e30f : lg[2] * SCALE_;
    float l3 = dead ? -1e30f : lg[3] * SCALE_;
    float m0 = l0, m1 = l1, m2 = l2, m3 = l3;
#pragma unroll
    for (int o = 1; o < 16; o <<= 1) {
      m0 = fmaxf(m0, __shfl_xor(m0, o)); m1 = fmaxf(m1, __shfl_xor(m1, o));
      m2 = fmaxf(m2, __shfl_xor(m2, o)); m3 = fmaxf(m3, __shfl_xor(m3, o));
    }
    float e0 = __expf(l0 - m0), e1 = __expf(l1 - m1);
    float e2 = __expf(l2 - m2), e3 = __expf(l3 - m3);
    float t0 = e0, t1 = e1, t2 = e2, t3 = e3;
#pragma unroll
    for (int o = 1; o < 16; o <<= 1) {
      t0 += __shfl_xor(t0, o); t1 += __shfl_xor(t1, o);
      t2 += __shfl_xor(t2, o); t3 += __shfl_xor(t3, o);
    }
    float a0 = e0 / t0 + EPS_, a1 = e1 / t1 + EPS_;
    float a2 = e2 / t2 + EPS_, a3 = e3 / t3 + EPS_;
    dden += a0 + a1 + a2 + a3;
    uint2 pk;
    pk.x = pk2(a0, a1); pk.y = pk2(a2, a3);
    int s = lane & 15;
    int nn = w * 64 + u * 16 + (lane >> 4) * 4;
    *(uint2*)((char*)att + s * 528 + nn * 2) = pk;
  }
  dden += __shfl_xor(dden, 16);
  dden += __shfl_xor(dden, 32);
  if (lane < 16) redd[w][lane] = dden;
  __syncthreads();
  if (t < S_)
    den_part[((size_t)b * NCH_ + chunk) * S_ + t] =
        redd[0][t] + redd[1][t] + redd[2][t] + redd[3][t];

  f32x4 acc[2] = {};
#pragma unroll
  for (int ks = 0; ks < 8; ks++) {
    bf16x8 pa = *(const bf16x8*)((const char*)att + (lane & 15) * 528 +
                                 (ks * 32 + (lane >> 4) * 8) * 2);
    size_t nb = (size_t)b * 128 + chunk * 8 + ks;
#pragma unroll
    for (int j = 0; j < 2; j++) {
      bf16x8 vb = *(const bf16x8*)(v_frag + (nb * 8 + (w * 2 + j)) * 512 + lane * 8);
      acc[j] = __builtin_amdgcn_mfma_f32_16x16x32_bf16(pa, vb, acc[j], 0, 0, 0);
    }
  }
#pragma unroll
  for (int j = 0; j < 2; j++)
#pragma unroll
    for (int r = 0; r < 4; r++) {
      int s = (lane >> 4) * 4 + r;
      if (s < S_) {
        int k = w * 32 + j * 16 + (lane & 15);
        num_part[(((size_t)b * NCH_ + chunk) * S_ + s) * 128 + k] = acc[j][r];
      }
    }
}

// ---------------- K63: finalize, GRU, MLP -> slots; packed bf16 weights ----------------
__global__ __launch_bounds__(256) void k63_final(const float* __restrict__ num_part,
                                                 const float* __restrict__ den_part,
                                                 float* __restrict__ slots,
                                                 const unsigned int* __restrict__ wihP,
                                                 const unsigned int* __restrict__ whhP,
                                                 const float* __restrict__ b_ih,
                                                 const float* __restrict__ b_hh,
                                                 const float* __restrict__ lmw,
                                                 const float* __restrict__ lmb,
                                                 const unsigned int* __restrict__ w1P,
                                                 const float* __restrict__ bb1,
                                                 const unsigned int* __restrict__ w2P,
                                                 const float* __restrict__ bb2,
                                                 const float* __restrict__ lsw,
                                                 const float* __restrict__ lsb,
                                                 const unsigned int* __restrict__ WqP,
                                                 float* __restrict__ qbuf,
                                                 float* __restrict__ outp,
                                                 int cq, int wout) {
  int bs = blockIdx.x;
  int b = bs / S_, s = bs % S_;
  int t = threadIdx.x;
  int j = t & 127, half = t >> 7;
  __shared__ float u[128], h[128], gp[3][128], m[128], hid[256], sjs[128], op[128];
  __shared__ float ns[128], snq[128];
  __shared__ float red2a[2], red2b[2];

  if (half == 0) {
    float den = 0.f;
#pragma unroll
    for (int c = 0; c < NCH_; c++) den += den_part[((size_t)b * NCH_ + c) * S_ + s];
    float uj = 0.f;
#pragma unroll
    for (int c = 0; c < NCH_; c++) uj += num_part[(((size_t)b * NCH_ + c) * S_ + s) * 128 + j];
    u[j] = uj / den;
  } else {
    h[j] = slots[((size_t)b * S_ + s) * 128 + j];
  }
  __syncthreads();

  {
    const unsigned int* wP = half ? whhP : wihP;
    const float* sv = half ? h : u;
    float g0 = 0.f, g1 = 0.f, g2 = 0.f;
#pragma unroll 8
    for (int kkp = 0; kkp < 64; kkp++) {
      float s0 = sv[2 * kkp], s1 = sv[2 * kkp + 1];
      unsigned int a0 = wP[kkp * 384 + j];
      unsigned int a1 = wP[kkp * 384 + 128 + j];
      unsigned int a2 = wP[kkp * 384 + 256 + j];
      g0 += b2f(a0) * s0 + b2f(a0 >> 16) * s1;
      g1 += b2f(a1) * s0 + b2f(a1 >> 16) * s1;
      g2 += b2f(a2) * s0 + b2f(a2 >> 16) * s1;
    }
    if (half) { gp[0][j] = g0; gp[1][j] = g1; gp[2][j] = g2; }
    __syncthreads();
    float sj = 0.f;
    if (half == 0) {
      float gr = g0 + b_ih[j]       + gp[0][j] + b_hh[j];
      float gz = g1 + b_ih[128 + j] + gp[1][j] + b_hh[128 + j];
      float r = 1.f / (1.f + __expf(-gr));
      float z = 1.f / (1.f + __expf(-gz));
      float nn = tanhf(g2 + b_ih[256 + j] + r * (gp[2][j] + b_hh[256 + j]));
      sj = (1.f - z) * nn + z * h[j];
      sjs[j] = sj;
    }
    float sv2 = sj, sq2 = sj * sj;
#pragma unroll
    for (int o = 1; o < 64; o <<= 1) { sv2 += __shfl_xor(sv2, o); sq2 += __shfl_xor(sq2, o); }
    if (half == 0 && (t & 63) == 0) { red2a[t >> 6] = sv2; red2b[t >> 6] = sq2; }
    __syncthreads();
    float mean = (red2a[0] + red2a[1]) * (1.f / 128.f);
    float var  = (red2b[0] + red2b[1]) * (1.f / 128.f) - mean * mean;
    float rstd = rsqrtf(var + LN_EPS_);
    if (half == 0) m[j] = (sj - mean) * rstd * lmw[j] + lmb[j];
  }
  __syncthreads();

  {
    float a = bb1[t];
#pragma unroll 8
    for (int kkp = 0; kkp < 64; kkp++) {
      unsigned int wv = w1P[kkp * 256 + t];
      a += b2f(wv) * m[2 * kkp] + b2f(wv >> 16) * m[2 * kkp + 1];
    }
    hid[t] = fmaxf(a, 0.f);
  }
  __syncthreads();

  {
    const float* hp = hid + half * 128;
    float o2 = 0.f;
#pragma unroll 8
    for (int hhp = 0; hhp < 64; hhp++) {
      unsigned int wv = w2P[(half * 64 + hhp) * 128 + j];
      o2 += b2f(wv) * hp[2 * hhp] + b2f(wv >> 16) * hp[2 * hhp + 1];
    }
    if (half) op[j] = o2;
    __syncthreads();
    if (half == 0) {
      float ov = sjs[j] + bb2[j] + o2 + op[j];
      slots[((size_t)b * S_ + s) * 128 + j] = ov;
      if (wout) outp[((size_t)b * S_ + s) * 128 + j] = ov;
      ns[j] = ov;
    }
  }
  __syncthreads();

  if (cq) {   // fused q for next iteration: q = LN_slot(new_slots) * Wq^T
    float vv = (half == 0) ? ns[j] : 0.f;
    float s1 = vv, s2 = vv * vv;
#pragma unroll
    for (int o = 1; o < 64; o <<= 1) { s1 += __shfl_xor(s1, o); s2 += __shfl_xor(s2, o); }
    if (half == 0 && (t & 63) == 0) { red2a[t >> 6] = s1; red2b[t >> 6] = s2; }
    __syncthreads();
    float mean = (red2a[0] + red2a[1]) * (1.f / 128.f);
    float var  = (red2b[0] + red2b[1]) * (1.f / 128.f) - mean * mean;
    float rstd = rsqrtf(var + LN_EPS_);
    if (half == 0) snq[j] = (ns[j] - mean) * rstd * lsw[j] + lsb[j];
    __syncthreads();
    const float* sp = snq + half * 64;
    float qv = 0.f;
#pragma unroll 8
    for (int m2 = 0; m2 < 32; m2++) {
      unsigned int wv = WqP[(half * 32 + m2) * 128 + j];
      qv += b2f(wv) * sp[2 * m2] + b2f(wv >> 16) * sp[2 * m2 + 1];
    }
    if (half) op[j] = qv;
    __syncthreads();
    if (half == 0) qbuf[(size_t)bs * 128 + j] = qv + op[j];
  }
}

extern "C" void kernel_launch(void* const* d_in, const int* in_sizes, int n_in,
                              void* d_out, int out_size, void* d_ws, size_t ws_size,
                              hipStream_t stream) {
  (void)in_sizes; (void)n_in; (void)out_size; (void)ws_size;
  const float* inputs     = (const float*)d_in[0];
  const float* slots_init = (const float*)d_in[1];
  const float* slots_mu   = (const float*)d_in[2];
  const float* slots_ls   = (const float*)d_in[3];
  const float* ln_in_w    = (const float*)d_in[4];
  const float* ln_in_b    = (const float*)d_in[5];
  const float* ln_slot_w  = (const float*)d_in[6];
  const float* ln_slot_b  = (const float*)d_in[7];
  const float* ln_mlp_w   = (const float*)d_in[8];
  const float* ln_mlp_b   = (const float*)d_in[9];
  const float* Wq         = (const float*)d_in[10];
  const float* Wk         = (const float*)d_in[11];
  const float* Wv         = (const float*)d_in[12];
  const float* w_ih       = (const float*)d_in[13];
  const float* w_hh       = (const float*)d_in[14];
  const float* b_ih       = (const float*)d_in[15];
  const float* b_hh       = (const float*)d_in[16];
  const float* mlp_w1     = (const float*)d_in[17];
  const float* mlp_b1     = (const float*)d_in[18];
  const float* mlp_w2     = (const float*)d_in[19];
  const float* mlp_b2     = (const float*)d_in[20];

  uintptr_t p = (uintptr_t)d_ws;
  auto carve = [&](size_t bytes) -> void* {
    void* r = (void*)p;
    p += (bytes + 255) & ~(size_t)255;
    return r;
  };
  unsigned short* k_frag = (unsigned short*)carve((size_t)B_ * N_ * K_ * 2);
  unsigned short* v_frag = (unsigned short*)carve((size_t)B_ * K_ * N_ * 2);
  unsigned short* W2pk   = (unsigned short*)carve((size_t)256 * 256 * 2);
  float* c1c2  = (float*)carve((size_t)256 * 2 * 4);
  unsigned int* wihP = (unsigned int*)carve((size_t)64 * 384 * 4);
  unsigned int* whhP = (unsigned int*)carve((size_t)64 * 384 * 4);
  unsigned int* w1P  = (unsigned int*)carve((size_t)64 * 256 * 4);
  unsigned int* w2P  = (unsigned int*)carve((size_t)128 * 128 * 4);
  unsigned int* WqP  = (unsigned int*)carve((size_t)64 * 128 * 4);
  float* WqT   = (float*)carve((size_t)128 * 128 * 4);
  float* qbuf     = (float*)carve((size_t)B_ * S_ * K_ * 4);
  float* slots    = (float*)carve((size_t)B_ * S_ * K_ * 4);
  float* den_part = (float*)carve((size_t)B_ * NCH_ * S_ * 4);
  float* num_part = (float*)carve((size_t)B_ * NCH_ * S_ * K_ * 4);

  kprep<<<801, 256, 0, stream>>>(Wk, Wv, ln_in_w, ln_in_b, W2pk, c1c2,
                                 slots_init, slots_mu, slots_ls, slots,
                                 w_ih, w_hh, wihP, whhP, mlp_w1, w1P, mlp_w2, w2P,
                                 Wq, WqT, WqP);
  k12_lngemm<<<(B_ * N_) / 64, 256, 0, stream>>>(inputs, c1c2, W2pk, k_frag, v_frag);
  k3_q<<<B_ * S_, 128, 0, stream>>>(slots, ln_slot_w, ln_slot_b, WqT, qbuf);

  for (int it = 0; it < ITERS_; ++it) {
    k45_attn<<<B_ * NCH_, 256, 0, stream>>>(k_frag, v_frag, qbuf, num_part, den_part);
    k63_final<<<B_ * S_, 256, 0, stream>>>(num_part, den_part, slots,
                                           wihP, whhP, b_ih, b_hh,
                                           ln_mlp_w, ln_mlp_b,
                                           w1P, mlp_b1, w2P, mlp_b2,
                                           ln_slot_w, ln_slot_b, WqP, qbuf,
                                           (float*)d_out,
                                           (it < ITERS_ - 1) ? 1 : 0,
                                           (it == ITERS_ - 1) ? 1 : 0);
  }
}